// Round 8
// baseline (513.087 us; speedup 1.0000x reference)
//
#include <hip/hip_runtime.h>

#define NN    2048
#define DIN   768
#define DOUT  1024
#define NH    8
#define HD    128
#define SCALEF 0.08838834764831845f
#define NEGF  (-1.0e9f)
#define EPSF  1e-5f
#define EXPSHIFT 16.0f

typedef __attribute__((ext_vector_type(4))) float f32x4;
typedef __attribute__((ext_vector_type(8))) short bf16x8;

// workspace layout (float-slot offsets)
#define OFF_OBF  0                         // bf16 O [2048][1024]
#define OFF_WOT  1048576                   // bf16 wo^T [768][1024]
#define OFF_YACC 1441792                   // f32 [2048][768]
#define OFF_Q    3686400                   // bf16 [8][2048][128]
#define OFF_K    4734976
#define OFF_VB   5783552                   // bf16 [2048][1024]
#define OFF_VT   6832128                   // bf16 [8][128][2048]
#define OFF_XB   7880704                   // bf16 [2048][768]
#define OFF_WT   8667136                   // bf16 [3][1024][768]
#define OFF_GQ   9846784
#define OFF_GK   9863168

__device__ __forceinline__ short f2bf(float f) {
  union { float f; unsigned u; } v; v.f = f;
  unsigned r = v.u + 0x7FFF + ((v.u >> 16) & 1);
  return (short)(r >> 16);
}
__device__ __forceinline__ float bf2f(short s) {
  union { unsigned u; float f; } v; v.u = ((unsigned)(unsigned short)s) << 16;
  return v.f;
}

// ---------------- fused preprocessing: cast_x | w_cast_t | wo_t ----------------
__global__ __launch_bounds__(256) void k_prep(const float* __restrict__ x,
                                              short* __restrict__ xb,
                                              const float* __restrict__ wq,
                                              const float* __restrict__ wk,
                                              const float* __restrict__ wv,
                                              short* __restrict__ Wt,
                                              const float* __restrict__ wo,
                                              short* __restrict__ wot) {
  const int bid = blockIdx.x;
  const int tid = threadIdx.x;
  if (bid < 1536) {  // cast x -> bf16
    int idx = bid * 256 + tid;
    float4 v = ((const float4*)x)[idx];
    union { short s[4]; float2 f; } u;
    u.s[0] = f2bf(v.x); u.s[1] = f2bf(v.y); u.s[2] = f2bf(v.z); u.s[3] = f2bf(v.w);
    ((float2*)xb)[idx] = u.f;
    return;
  }
  __shared__ float t[64][65];
  if (bid < 2112) {  // W[768][1024] -> Wt[z][1024][768] bf16
    const int w = bid - 1536;
    const int z = w / 192, rem = w % 192;
    const int c0 = (rem % 16) * 64, k0 = (rem / 16) * 64;
    const float* Wm = (z == 0) ? wq : (z == 1) ? wk : wv;
#pragma unroll
    for (int l = 0; l < 4; ++l) {
      int f = tid + l * 256;
      int r = f >> 4, c4 = (f & 15) * 4;
      *(float4*)&t[r][c4] = *(const float4*)(Wm + (size_t)(k0 + r) * DOUT + c0 + c4);
    }
    __syncthreads();
    int r2 = tid >> 2, q = tid & 3;
    union { short s[16]; float4 f[2]; } buf;
#pragma unroll
    for (int jj = 0; jj < 16; ++jj) buf.s[jj] = f2bf(t[q * 16 + jj][r2]);
    short* dst = Wt + (size_t)z * (1024 * 768) + (size_t)(c0 + r2) * 768 + k0 + q * 16;
    ((float4*)dst)[0] = buf.f[0];
    ((float4*)dst)[1] = buf.f[1];
  } else {  // wo[1024][768] -> wot[768][1024] bf16
    const int w = bid - 2112;
    const int c0 = (w % 12) * 64, k0 = (w / 12) * 64;
#pragma unroll
    for (int l = 0; l < 4; ++l) {
      int f = tid + l * 256;
      int r = f >> 4, c4 = (f & 15) * 4;
      *(float4*)&t[r][c4] = *(const float4*)(wo + (size_t)(k0 + r) * DIN + c0 + c4);
    }
    __syncthreads();
    int r2 = tid >> 2, q = tid & 3;
    union { short s[16]; float4 f[2]; } buf;
#pragma unroll
    for (int jj = 0; jj < 16; ++jj) buf.s[jj] = f2bf(t[q * 16 + jj][r2]);
    short* dst = wot + (size_t)(c0 + r2) * DOUT + k0 + q * 16;
    ((float4*)dst)[0] = buf.f[0];
    ((float4*)dst)[1] = buf.f[1];
  }
}

// ---------------- QKV projection: 64x128 tiles, LDS-staged B panel ----------------
__global__ __launch_bounds__(256) void k_qkv(const short* __restrict__ xb,
                                             const short* __restrict__ Wt,
                                             const float* __restrict__ bq,
                                             const float* __restrict__ bk,
                                             const float* __restrict__ bv,
                                             short* __restrict__ Qb,
                                             short* __restrict__ Kb,
                                             short* __restrict__ Vb) {
  const int n0 = blockIdx.x * 128;  // 0..2944 over 3072
  const int i0 = blockIdx.y * 64;   // 0..1984
  const int mat = n0 >> 10;
  const int cl = n0 & 1023;
  const float* bias = (mat == 0) ? bq : (mat == 1) ? bk : bv;
  const short* Wm = Wt + (size_t)mat * (1024 * 768);
  const int tid = threadIdx.x, lane = tid & 63, wave = tid >> 6;
  const int ln = lane & 15, quad = lane >> 4, q8 = quad * 8;
  __shared__ __align__(16) short Bs[2][128][56];  // stride 112B: 16B-aligned, 2-way max
  const int brow = tid >> 1, bseg = (tid & 1) * 16;
  const short* gB = Wm + (size_t)(cl + brow) * DIN + bseg;
  {
    bf16x8 b0 = *(const bf16x8*)(gB);
    bf16x8 b1 = *(const bf16x8*)(gB + 8);
    *(bf16x8*)&Bs[0][brow][bseg] = b0;
    *(bf16x8*)&Bs[0][brow][bseg + 8] = b1;
  }
  bf16x8 cb0 = *(const bf16x8*)(gB + 32);
  bf16x8 cb1 = *(const bf16x8*)(gB + 40);
  __syncthreads();
  f32x4 acc[8];
#pragma unroll
  for (int nt = 0; nt < 8; ++nt) acc[nt] = (f32x4){0.f, 0.f, 0.f, 0.f};
  const short* a0 = xb + (size_t)(i0 + 16 * wave + ln) * DIN + q8;
  for (int ks = 0; ks < 24; ++ks) {
    const int bufc = ks & 1;
    bf16x8 nb0, nb1;
    if (ks < 22) {
      nb0 = *(const bf16x8*)(gB + 32 * (ks + 2));
      nb1 = *(const bf16x8*)(gB + 32 * (ks + 2) + 8);
    }
    bf16x8 A0 = *(const bf16x8*)(a0 + 32 * ks);
#pragma unroll
    for (int nt = 0; nt < 8; ++nt) {
      bf16x8 B = *(const bf16x8*)&Bs[bufc][16 * nt + ln][q8];
      acc[nt] = __builtin_amdgcn_mfma_f32_16x16x32_bf16(A0, B, acc[nt], 0, 0, 0);
    }
    if (ks < 23) {
      *(bf16x8*)&Bs[bufc ^ 1][brow][bseg] = cb0;
      *(bf16x8*)&Bs[bufc ^ 1][brow][bseg + 8] = cb1;
    }
    __syncthreads();
    if (ks < 22) { cb0 = nb0; cb1 = nb1; }
  }
#pragma unroll
  for (int nt = 0; nt < 8; ++nt) {
    int cg = cl + 16 * nt + ln;
    float bb = bias[cg];
#pragma unroll
    for (int reg = 0; reg < 4; ++reg) {
      int rr = i0 + 16 * wave + quad * 4 + reg;
      short s = f2bf(acc[nt][reg] + bb);
      if (mat == 2) {
        Vb[(size_t)rr * 1024 + cg] = s;
      } else {
        int h = cg >> 7, d = cg & 127;
        (mat == 0 ? Qb : Kb)[((size_t)h * NN + rr) * HD + d] = s;
      }
    }
  }
}

// ---------------- fused: gates (bid<2048, shuffle-reduce) | Vb->Vt (bid>=2048) ------
__global__ __launch_bounds__(256) void k_vtg(const short* __restrict__ Qb,
                                             const short* __restrict__ Kb,
                                             const float* __restrict__ gqw,
                                             const float* __restrict__ gqb,
                                             const float* __restrict__ gkw,
                                             const float* __restrict__ gkb,
                                             float* __restrict__ GQ,
                                             float* __restrict__ GK,
                                             const short* __restrict__ Vb,
                                             short* __restrict__ Vt) {
  const int bid = blockIdx.x;
  const int tid = threadIdx.x;
  __shared__ __align__(16) char smem[17408];
  if (bid < 2048) {  // gates
    const int i = bid;
    const int lane = tid & 63, wave = tid >> 6;
    float aq[NH] = {}, ak[NH] = {};
    for (int d = tid; d < DOUT; d += 256) {
      int h = d >> 7, dd = d & 127;
      float qv = bf2f(Qb[((size_t)h * NN + i) * HD + dd]);
      float kv = bf2f(Kb[((size_t)h * NN + i) * HD + dd]);
      float4 ga = *(const float4*)(gqw + (size_t)d * NH);
      float4 gb = *(const float4*)(gqw + (size_t)d * NH + 4);
      float4 ha = *(const float4*)(gkw + (size_t)d * NH);
      float4 hb = *(const float4*)(gkw + (size_t)d * NH + 4);
      aq[0] = fmaf(qv, ga.x, aq[0]); aq[1] = fmaf(qv, ga.y, aq[1]);
      aq[2] = fmaf(qv, ga.z, aq[2]); aq[3] = fmaf(qv, ga.w, aq[3]);
      aq[4] = fmaf(qv, gb.x, aq[4]); aq[5] = fmaf(qv, gb.y, aq[5]);
      aq[6] = fmaf(qv, gb.z, aq[6]); aq[7] = fmaf(qv, gb.w, aq[7]);
      ak[0] = fmaf(kv, ha.x, ak[0]); ak[1] = fmaf(kv, ha.y, ak[1]);
      ak[2] = fmaf(kv, ha.z, ak[2]); ak[3] = fmaf(kv, ha.w, ak[3]);
      ak[4] = fmaf(kv, hb.x, ak[4]); ak[5] = fmaf(kv, hb.y, ak[5]);
      ak[6] = fmaf(kv, hb.z, ak[6]); ak[7] = fmaf(kv, hb.w, ak[7]);
    }
#pragma unroll
    for (int h = 0; h < NH; ++h) {
#pragma unroll
      for (int off = 1; off < 64; off <<= 1) {
        aq[h] += __shfl_xor(aq[h], off);
        ak[h] += __shfl_xor(ak[h], off);
      }
    }
    auto part = (float (*)[16])(smem);  // [4][16]
    if (lane == 0) {
#pragma unroll
      for (int h = 0; h < NH; ++h) {
        part[wave][h] = aq[h];
        part[wave][8 + h] = ak[h];
      }
    }
    __syncthreads();
    if (tid < 16) {
      float s = part[0][tid] + part[1][tid] + part[2][tid] + part[3][tid];
      if (tid < 8) GQ[(size_t)i * NH + tid] = tanhf(s + gqb[tid]);
      else GK[(size_t)i * NH + tid - 8] = tanhf(s + gkb[tid - 8]);
    }
  } else {  // Vb -> Vt[h][d][n]
    auto t = (short (*)[136])(smem);  // [64][136]
    const int w = bid - 2048;
    const int i0 = (w & 31) * 64, h = w >> 5;
#pragma unroll
    for (int l = 0; l < 2; ++l) {
      int f = tid + l * 256;
      int r = f >> 3, c8 = (f & 7) * 16;
      const short* src = Vb + (size_t)(i0 + r) * 1024 + h * HD + c8;
      *(bf16x8*)&t[r][c8] = *(const bf16x8*)src;
      *(bf16x8*)&t[r][c8 + 8] = *(const bf16x8*)(src + 8);
    }
    __syncthreads();
    int d = tid >> 1, half = tid & 1;
    union { short s[32]; float4 f[4]; } buf;
#pragma unroll
    for (int ii = 0; ii < 32; ++ii) buf.s[ii] = t[32 * half + ii][d];
    short* dst = Vt + (size_t)h * (HD * NN) + (size_t)d * NN + i0 + 32 * half;
#pragma unroll
    for (int q = 0; q < 4; ++q) ((float4*)dst)[q] = buf.f[q];
  }
}

// ---------------- fused scores + assemble (single-buffer Q/K, 7 blocks/CU) ----------
// Single-buffered Q/K staging cuts LDS 38.4->20.7KB -> 7 blocks/CU (28 waves):
// wave rotation hides the motif/store/barrier latencies the R7 profile showed
// (no pipe >35% busy at 36% occupancy). Loads still issued 2 heads ahead in regs.
__global__ __launch_bounds__(256, 6) void k_sa(const short* __restrict__ Qb,
                                               const short* __restrict__ Kb,
                                               const int* __restrict__ batch,
                                               const float* __restrict__ motif,
                                               const float* __restrict__ GQ,
                                               const float* __restrict__ GK,
                                               const float* __restrict__ Wh,
                                               const float* __restrict__ alpha_p,
                                               const float* __restrict__ beta_p,
                                               float* __restrict__ ATTN) {
  // XCD patch swizzle: 16x16 block patches per XCD
  const unsigned gid = blockIdx.y * gridDim.x + blockIdx.x;
  const unsigned xcd = gid & 7, idx = gid >> 3;
  const unsigned P = xcd + 8 * (idx >> 8);
  const unsigned r256 = idx & 255;
  const unsigned bx = 16 * (P & 3) + (r256 & 15);
  const unsigned by = 16 * (P >> 2) + (r256 >> 4);
  const int i0 = by * 32, j0 = bx * 32;

  const int tid = threadIdx.x, lane = tid & 63, wave = tid >> 6;
  const int wr = wave >> 1, wc = wave & 1;
  const int ln = lane & 15, quad = lane >> 4, q8 = quad * 8;

  __shared__ __align__(16) char smem[20736];
  auto Qs  = (short (*)[136])(smem);                // [32][136] bf16
  auto Ks  = (short (*)[136])(smem + 8704);         // [32][136] bf16
  auto oL  = (float (*)[36])(smem);                 // [32][36] f32 (aliases Qs)
  auto gqL = (float (*)[12])(smem + 17408);         // [32][12]
  auto gkL = (float (*)[12])(smem + 18944);         // [32][12]
  float* sW = (float*)(smem + 20480);               // [64]

  const int rA = 16 * wr + quad * 4;
  const int cA = 16 * wc + ln;

  const int srow = tid >> 3, sseg = (tid & 7) * 16;
  const short* gQ0 = Qb + (size_t)(i0 + srow) * HD + sseg;
  const short* gK0 = Kb + (size_t)(j0 + srow) * HD + sseg;
  const size_t hstep = (size_t)NN * HD;

  // prologue: stage head0 to LDS, hold head1 in regs
  {
    bf16x8 q0 = *(const bf16x8*)(gQ0);
    bf16x8 q1 = *(const bf16x8*)(gQ0 + 8);
    bf16x8 k0 = *(const bf16x8*)(gK0);
    bf16x8 k1 = *(const bf16x8*)(gK0 + 8);
    *(bf16x8*)&Qs[srow][sseg] = q0;
    *(bf16x8*)&Qs[srow][sseg + 8] = q1;
    *(bf16x8*)&Ks[srow][sseg] = k0;
    *(bf16x8*)&Ks[srow][sseg + 8] = k1;
  }
  bf16x8 cq0 = *(const bf16x8*)(gQ0 + hstep);
  bf16x8 cq1 = *(const bf16x8*)(gQ0 + hstep + 8);
  bf16x8 ck0 = *(const bf16x8*)(gK0 + hstep);
  bf16x8 ck1 = *(const bf16x8*)(gK0 + hstep + 8);
  if (tid < 64) {
    const int half = tid >> 5, r = tid & 31;
    const float* src = (half ? GK : GQ) + (size_t)((half ? j0 : i0) + r) * NH;
    float4 a = *(const float4*)src;
    float4 b = *(const float4*)(src + 4);
    float* dst = half ? &gkL[r][0] : &gqL[r][0];
    *(float4*)dst = a;
    *(float4*)(dst + 4) = b;
    sW[tid] = Wh[tid];
  }
  const int4 bi4 = *(const int4*)(batch + i0 + rA);
  const int bj = batch[j0 + cA];
  const float alpha = alpha_p[0], beta = beta_p[0];
  __syncthreads();

  f32x4 accS[NH], accT[NH];
#pragma unroll
  for (int h = 0; h < NH; ++h) {
    accS[h] = (f32x4){0.f, 0.f, 0.f, 0.f};
    accT[h] = (f32x4){0.f, 0.f, 0.f, 0.f};
  }

#pragma unroll
  for (int h = 0; h < NH; ++h) {
    bf16x8 nq0, nq1, nk0, nk1;
    if (h < 6) {  // issue head h+2's loads (in flight across this head's MFMAs)
      const short* gq_ = gQ0 + (size_t)(h + 2) * hstep;
      const short* gk_ = gK0 + (size_t)(h + 2) * hstep;
      nq0 = *(const bf16x8*)(gq_);
      nq1 = *(const bf16x8*)(gq_ + 8);
      nk0 = *(const bf16x8*)(gk_);
      nk1 = *(const bf16x8*)(gk_ + 8);
    }
#pragma unroll
    for (int ks = 0; ks < 4; ++ks) {
      bf16x8 aS = *(const bf16x8*)&Qs[16 * wr + ln][ks * 32 + q8];
      bf16x8 bS = *(const bf16x8*)&Ks[16 * wc + ln][ks * 32 + q8];
      accS[h] = __builtin_amdgcn_mfma_f32_16x16x32_bf16(aS, bS, accS[h], 0, 0, 0);
      bf16x8 aT = *(const bf16x8*)&Ks[16 * wr + ln][ks * 32 + q8];
      bf16x8 bT = *(const bf16x8*)&Qs[16 * wc + ln][ks * 32 + q8];
      accT[h] = __builtin_amdgcn_mfma_f32_16x16x32_bf16(aT, bT, accT[h], 0, 0, 0);
    }
    __syncthreads();  // all reads of Qs/Ks done
    if (h < 7) {      // overwrite with head h+1 (held in regs since last iter)
      *(bf16x8*)&Qs[srow][sseg] = cq0;
      *(bf16x8*)&Qs[srow][sseg + 8] = cq1;
      *(bf16x8*)&Ks[srow][sseg] = ck0;
      *(bf16x8*)&Ks[srow][sseg + 8] = ck1;
      __syncthreads();
    }
    if (h < 6) { cq0 = nq0; cq1 = nq1; ck0 = nk0; ck1 = nk1; }
  }

  // mask + scale S
  int okm[4];
  okm[0] = (bi4.x == bj); okm[1] = (bi4.y == bj);
  okm[2] = (bi4.z == bj); okm[3] = (bi4.w == bj);
#pragma unroll
  for (int reg = 0; reg < 4; ++reg)
#pragma unroll
    for (int h = 0; h < NH; ++h)
      accS[h][reg] = okm[reg] ? accS[h][reg] * SCALEF : NEGF;

  // per-head epilogue: motif 2-ahead reg pipeline, LDS transpose, full-line stores
  const int orow = tid >> 3, oslot = (tid & 7) * 4;
  union { float4 v; float f[4]; } moc, mon, mo2;
  moc.v = *(const float4*)(motif + ((size_t)(j0 + cA)) * NN + i0 + rA);
  mon.v = *(const float4*)(motif + ((size_t)(NN + j0 + cA)) * NN + i0 + rA);
#pragma unroll
  for (int h = 0; h < NH; ++h) {
    if (h < 6)
      mo2.v = *(const float4*)(motif + ((size_t)(h + 2) * NN + j0 + cA) * NN + i0 + rA);
    float w8[NH];
#pragma unroll
    for (int h2 = 0; h2 < NH; ++h2) w8[h2] = sW[h2 * NH + h];
    const float gkj = gkL[cA][h];
#pragma unroll
    for (int reg = 0; reg < 4; ++reg) {
      float tv = okm[reg] ? accT[h][reg] * SCALEF : NEGF;
      float hm = 0.f;
#pragma unroll
      for (int h2 = 0; h2 < NH; ++h2) hm = fmaf(accS[h2][reg], w8[h2], hm);
      float o = accS[h][reg] * (1.f + gqL[rA + reg][h] + gkj) +
                alpha * tv + beta * moc.f[reg] + hm;
      oL[rA + reg][cA] = o;
    }
    __syncthreads();
    float4 ov = *(const float4*)&oL[orow][oslot];
    *(float4*)(ATTN + ((size_t)h * NN + i0 + orow) * NN + j0 + oslot) = ov;
    if (h < 7) __syncthreads();
    moc.v = mon.v;
    mon.v = mo2.v;
  }
}

// ---------------- P@V: 16-row strips x 4 j-quarter waves, reg-prefetched V --------
__global__ __launch_bounds__(256, 4) void k_pv(const float* __restrict__ ATTN,
                                               const short* __restrict__ Vt,
                                               short* __restrict__ Obf) {
  const int bid = blockIdx.x;      // 0..1023
  const int h = bid & 7;           // head -> XCD (V stays L2-resident)
  const int i0 = (bid >> 3) * 16;  // 128 strips
  const int tid = threadIdx.x, lane = tid & 63, wave = tid >> 6;
  const int ln = lane & 15, quad = lane >> 4, q8 = quad * 8;
  __shared__ float accL[4][16][140];
  __shared__ float SUML[4][16];
  const int jbase = wave * 512;
  const float* arow = ATTN + ((size_t)h * NN + i0 + ln) * NN + jbase;
  const short* vbase = Vt + (size_t)h * (HD * NN) + jbase;
  f32x4 acc[8];
#pragma unroll
  for (int nt = 0; nt < 8; ++nt) acc[nt] = (f32x4){0.f, 0.f, 0.f, 0.f};
  float rowsum = 0.f;
  // prologue: chunk 0's V fragments + ATTN into regs
  bf16x8 vc[8];
#pragma unroll
  for (int nt = 0; nt < 8; ++nt)
    vc[nt] = *(const bf16x8*)(vbase + (size_t)(16 * nt + ln) * NN + q8);
  float4 u1 = *(const float4*)(arow + q8);
  float4 u2 = *(const float4*)(arow + q8 + 4);
#pragma unroll
  for (int c = 0; c < 16; ++c) {
    const int jk = c * 32;
    bf16x8 vn[8];
    float4 n1, n2;
    if (c < 15) {  // issue next chunk's loads FIRST (hide under exp+MFMA)
#pragma unroll
      for (int nt = 0; nt < 8; ++nt)
        vn[nt] = *(const bf16x8*)(vbase + (size_t)(16 * nt + ln) * NN + jk + 32 + q8);
      n1 = *(const float4*)(arow + jk + 32 + q8);
      n2 = *(const float4*)(arow + jk + 32 + q8 + 4);
    }
    float p0 = __expf(u1.x - EXPSHIFT), p1 = __expf(u1.y - EXPSHIFT);
    float p2 = __expf(u1.z - EXPSHIFT), p3 = __expf(u1.w - EXPSHIFT);
    float p4 = __expf(u2.x - EXPSHIFT), p5 = __expf(u2.y - EXPSHIFT);
    float p6 = __expf(u2.z - EXPSHIFT), p7 = __expf(u2.w - EXPSHIFT);
    rowsum += ((p0 + p1) + (p2 + p3)) + ((p4 + p5) + (p6 + p7));
    bf16x8 a;
    a[0] = f2bf(p0); a[1] = f2bf(p1); a[2] = f2bf(p2); a[3] = f2bf(p3);
    a[4] = f2bf(p4); a[5] = f2bf(p5); a[6] = f2bf(p6); a[7] = f2bf(p7);
#pragma unroll
    for (int nt = 0; nt < 8; ++nt)
      acc[nt] = __builtin_amdgcn_mfma_f32_16x16x32_bf16(a, vc[nt], acc[nt], 0, 0, 0);
    if (c < 15) {
#pragma unroll
      for (int nt = 0; nt < 8; ++nt) vc[nt] = vn[nt];
      u1 = n1; u2 = n2;
    }
  }
  rowsum += __shfl_xor(rowsum, 16);
  rowsum += __shfl_xor(rowsum, 32);
  if (lane < 16) SUML[wave][ln] = rowsum;
#pragma unroll
  for (int nt = 0; nt < 8; ++nt)
#pragma unroll
    for (int reg = 0; reg < 4; ++reg)
      accL[wave][quad * 4 + reg][16 * nt + ln] = acc[nt][reg];
  __syncthreads();
  const int r = tid >> 4, d0 = (tid & 15) * 8;
  const float inv = 1.0f / (SUML[0][r] + SUML[1][r] + SUML[2][r] + SUML[3][r]);
  union { short s[8]; bf16x8 v; } ob;
#pragma unroll
  for (int e = 0; e < 8; ++e) {
    float s = accL[0][r][d0 + e] + accL[1][r][d0 + e] +
              accL[2][r][d0 + e] + accL[3][r][d0 + e];
    ob.s[e] = f2bf(s * inv);
  }
  *(bf16x8*)(Obf + (size_t)(i0 + r) * DOUT + h * HD + d0) = ob.v;
}

// ---------------- out-proj: 64x64 tiles, LDS-staged B panel ----------------
__global__ __launch_bounds__(256) void k_outproj(const short* __restrict__ Obf,
                                                 const short* __restrict__ wot,
                                                 float* __restrict__ YACC) {
  const int n0 = blockIdx.x * 64;   // 768 cols -> 12
  const int i0 = blockIdx.y * 64;   // 2048 rows -> 32
  const int tid = threadIdx.x, lane = tid & 63, wave = tid >> 6;
  const int ln = lane & 15, quad = lane >> 4, q8 = quad * 8;
  __shared__ __align__(16) short Bs[2][64][56];
  const int brow = tid >> 2, bseg = (tid & 3) * 8;  // 64 rows x 4 segs of 16B
  const short* gB = wot + (size_t)(n0 + brow) * DOUT + bseg;
  {
    bf16x8 b0 = *(const bf16x8*)(gB);
    *(bf16x8*)&Bs[0][brow][bseg] = b0;
  }
  bf16x8 cb0 = *(const bf16x8*)(gB + 32);
  __syncthreads();
  f32x4 acc[4];
#pragma unroll
  for (int nt = 0; nt < 4; ++nt) acc[nt] = (f32x4){0.f, 0.f, 0.f, 0.f};
  const short* a0 = Obf + (size_t)(i0 + 16 * wave + ln) * DOUT + q8;
  for (int ks = 0; ks < 32; ++ks) {
    const int bufc = ks & 1;
    bf16x8 nb0;
    if (ks < 30) nb0 = *(const bf16x8*)(gB + 32 * (ks + 2));
    bf16x8 A0 = *(const bf16x8*)(a0 + 32 * ks);
#pragma unroll
    for (int nt = 0; nt < 4; ++nt) {
      bf16x8 B = *(const bf16x8*)&Bs[bufc][16 * nt + ln][q8];
      acc[nt] = __builtin_amdgcn_mfma_f32_16x16x32_bf16(A0, B, acc[nt], 0, 0, 0);
    }
    if (ks < 31) *(bf16x8*)&Bs[bufc ^ 1][brow][bseg] = cb0;
    __syncthreads();
    if (ks < 30) cb0 = nb0;
  }
#pragma unroll
  for (int nt = 0; nt < 4; ++nt) {
    int cg = n0 + 16 * nt + ln;
#pragma unroll
    for (int reg = 0; reg < 4; ++reg) {
      int rr = i0 + 16 * wave + quad * 4 + reg;
      YACC[(size_t)rr * DIN + cg] = acc[nt][reg];
    }
  }
}

// ---------------- bias + residual + LayerNorm (shuffle-reduce, 2 barriers) --------
__global__ __launch_bounds__(256) void k_ln(const float* __restrict__ YACC,
                                            const float* __restrict__ x,
                                            const float* __restrict__ wo_b,
                                            const float* __restrict__ g,
                                            const float* __restrict__ b,
                                            float* __restrict__ y) {
  const int i = blockIdx.x;
  const int tid = threadIdx.x;
  const int lane = tid & 63, wave = tid >> 6;
  float v[3];
#pragma unroll
  for (int t = 0; t < 3; ++t) {
    int cc = tid + t * 256;
    v[t] = YACC[(size_t)i * DIN + cc] + wo_b[cc] + x[(size_t)i * DIN + cc];
  }
  __shared__ float p1[4], p2[4];
  float s = v[0] + v[1] + v[2];
#pragma unroll
  for (int off = 1; off < 64; off <<= 1) s += __shfl_xor(s, off);
  if (lane == 0) p1[wave] = s;
  __syncthreads();
  const float mu = (p1[0] + p1[1] + p1[2] + p1[3]) * (1.0f / DIN);
  float q = 0.f;
#pragma unroll
  for (int t = 0; t < 3; ++t) {
    float d = v[t] - mu;
    q += d * d;
  }
#pragma unroll
  for (int off = 1; off < 64; off <<= 1) q += __shfl_xor(q, off);
  if (lane == 0) p2[wave] = q;
  __syncthreads();
  const float rs = rsqrtf((p2[0] + p2[1] + p2[2] + p2[3]) * (1.0f / DIN) + EPSF);
#pragma unroll
  for (int t = 0; t < 3; ++t) {
    int cc = tid + t * 256;
    y[(size_t)i * DIN + cc] = (v[t] - mu) * rs * g[cc] + b[cc];
  }
}

extern "C" void kernel_launch(void* const* d_in, const int* in_sizes, int n_in,
                              void* d_out, int out_size, void* d_ws, size_t ws_size,
                              hipStream_t stream) {
  (void)in_sizes; (void)n_in; (void)out_size; (void)ws_size;
  const float* x       = (const float*)d_in[0];
  const int*   batch   = (const int*)d_in[1];
  const float* motif   = (const float*)d_in[2];
  const float* wq_w    = (const float*)d_in[3];
  const float* wq_b    = (const float*)d_in[4];
  const float* wk_w    = (const float*)d_in[5];
  const float* wk_b    = (const float*)d_in[6];
  const float* wv_w    = (const float*)d_in[7];
  const float* wv_b    = (const float*)d_in[8];
  const float* wo_w    = (const float*)d_in[9];
  const float* wo_b    = (const float*)d_in[10];
  const float* ln_g    = (const float*)d_in[11];
  const float* ln_b    = (const float*)d_in[12];
  const float* alpha_p = (const float*)d_in[13];
  const float* beta_p  = (const float*)d_in[14];
  const float* gq_w    = (const float*)d_in[15];
  const float* gq_b    = (const float*)d_in[16];
  const float* gk_w    = (const float*)d_in[17];
  const float* gk_b    = (const float*)d_in[18];
  const float* headW   = (const float*)d_in[19];

  float* y    = (float*)d_out;
  float* ATTN = (float*)d_out + (size_t)NN * DIN;
  float* ws   = (float*)d_ws;
  short* Obf  = (short*)(ws + OFF_OBF);
  short* wot  = (short*)(ws + OFF_WOT);
  float* YACC = ws + OFF_YACC;
  short* Qb   = (short*)(ws + OFF_Q);
  short* Kb   = (short*)(ws + OFF_K);
  short* Vb   = (short*)(ws + OFF_VB);
  short* Vt   = (short*)(ws + OFF_VT);
  short* xb   = (short*)(ws + OFF_XB);
  short* Wt   = (short*)(ws + OFF_WT);
  float* GQ   = ws + OFF_GQ;
  float* GK   = ws + OFF_GK;

  k_prep<<<2304, 256, 0, stream>>>(x, xb, wq_w, wk_w, wv_w, Wt, wo_w, wot);
  k_qkv<<<dim3(24, 32), 256, 0, stream>>>(xb, Wt, wq_b, wk_b, wv_b, Qb, Kb, Vb);
  k_vtg<<<2304, 256, 0, stream>>>(Qb, Kb, gq_w, gq_b, gk_w, gk_b, GQ, GK, Vb, Vt);
  k_sa<<<dim3(64, 64), 256, 0, stream>>>(Qb, Kb, batch, motif, GQ, GK, headW,
                                         alpha_p, beta_p, ATTN);
  k_pv<<<1024, 256, 0, stream>>>(ATTN, Vt, Obf);
  k_outproj<<<dim3(12, 32), 256, 0, stream>>>(Obf, wot, YACC);
  k_ln<<<NN, 256, 0, stream>>>(YACC, x, wo_b, ln_g, ln_b, y);
}

// Round 9
// 455.030 us; speedup vs baseline: 1.1276x; 1.1276x over previous
//
#include <hip/hip_runtime.h>

#define NN    2048
#define DIN   768
#define DOUT  1024
#define NH    8
#define HD    128
#define SCALEF 0.08838834764831845f
#define NEGF  (-1.0e9f)
#define EPSF  1e-5f
#define EXPSHIFT 16.0f

typedef __attribute__((ext_vector_type(4))) float f32x4;
typedef __attribute__((ext_vector_type(8))) short bf16x8;

// workspace layout (float-slot offsets)
#define OFF_OBF  0                         // bf16 O [2048][1024]
#define OFF_WOT  1048576                   // bf16 wo^T [768][1024]
#define OFF_YACC 1441792                   // f32 [2048][768]
#define OFF_Q    3686400                   // bf16 [8][2048][128]
#define OFF_K    4734976
#define OFF_VB   5783552                   // bf16 [2048][1024]
#define OFF_VT   6832128                   // bf16 [8][128][2048]
#define OFF_XB   7880704                   // bf16 [2048][768]
#define OFF_WT   8667136                   // bf16 [3][1024][768]
#define OFF_GQ   9846784
#define OFF_GK   9863168

__device__ __forceinline__ short f2bf(float f) {
  union { float f; unsigned u; } v; v.f = f;
  unsigned r = v.u + 0x7FFF + ((v.u >> 16) & 1);
  return (short)(r >> 16);
}
__device__ __forceinline__ float bf2f(short s) {
  union { unsigned u; float f; } v; v.u = ((unsigned)(unsigned short)s) << 16;
  return v.f;
}

// ---------------- fused preprocessing: cast_x | w_cast_t | wo_t ----------------
__global__ __launch_bounds__(256) void k_prep(const float* __restrict__ x,
                                              short* __restrict__ xb,
                                              const float* __restrict__ wq,
                                              const float* __restrict__ wk,
                                              const float* __restrict__ wv,
                                              short* __restrict__ Wt,
                                              const float* __restrict__ wo,
                                              short* __restrict__ wot) {
  const int bid = blockIdx.x;
  const int tid = threadIdx.x;
  if (bid < 1536) {  // cast x -> bf16
    int idx = bid * 256 + tid;
    float4 v = ((const float4*)x)[idx];
    union { short s[4]; float2 f; } u;
    u.s[0] = f2bf(v.x); u.s[1] = f2bf(v.y); u.s[2] = f2bf(v.z); u.s[3] = f2bf(v.w);
    ((float2*)xb)[idx] = u.f;
    return;
  }
  __shared__ float t[64][65];
  if (bid < 2112) {  // W[768][1024] -> Wt[z][1024][768] bf16
    const int w = bid - 1536;
    const int z = w / 192, rem = w % 192;
    const int c0 = (rem % 16) * 64, k0 = (rem / 16) * 64;
    const float* Wm = (z == 0) ? wq : (z == 1) ? wk : wv;
#pragma unroll
    for (int l = 0; l < 4; ++l) {
      int f = tid + l * 256;
      int r = f >> 4, c4 = (f & 15) * 4;
      *(float4*)&t[r][c4] = *(const float4*)(Wm + (size_t)(k0 + r) * DOUT + c0 + c4);
    }
    __syncthreads();
    int r2 = tid >> 2, q = tid & 3;
    union { short s[16]; float4 f[2]; } buf;
#pragma unroll
    for (int jj = 0; jj < 16; ++jj) buf.s[jj] = f2bf(t[q * 16 + jj][r2]);
    short* dst = Wt + (size_t)z * (1024 * 768) + (size_t)(c0 + r2) * 768 + k0 + q * 16;
    ((float4*)dst)[0] = buf.f[0];
    ((float4*)dst)[1] = buf.f[1];
  } else {  // wo[1024][768] -> wot[768][1024] bf16
    const int w = bid - 2112;
    const int c0 = (w % 12) * 64, k0 = (w / 12) * 64;
#pragma unroll
    for (int l = 0; l < 4; ++l) {
      int f = tid + l * 256;
      int r = f >> 4, c4 = (f & 15) * 4;
      *(float4*)&t[r][c4] = *(const float4*)(wo + (size_t)(k0 + r) * DIN + c0 + c4);
    }
    __syncthreads();
    int r2 = tid >> 2, q = tid & 3;
    union { short s[16]; float4 f[2]; } buf;
#pragma unroll
    for (int jj = 0; jj < 16; ++jj) buf.s[jj] = f2bf(t[q * 16 + jj][r2]);
    short* dst = wot + (size_t)(c0 + r2) * DOUT + k0 + q * 16;
    ((float4*)dst)[0] = buf.f[0];
    ((float4*)dst)[1] = buf.f[1];
  }
}

// ---------------- QKV projection: 64x128 tiles, LDS-staged B panel ----------------
__global__ __launch_bounds__(256) void k_qkv(const short* __restrict__ xb,
                                             const short* __restrict__ Wt,
                                             const float* __restrict__ bq,
                                             const float* __restrict__ bk,
                                             const float* __restrict__ bv,
                                             short* __restrict__ Qb,
                                             short* __restrict__ Kb,
                                             short* __restrict__ Vb) {
  const int n0 = blockIdx.x * 128;  // 0..2944 over 3072
  const int i0 = blockIdx.y * 64;   // 0..1984
  const int mat = n0 >> 10;
  const int cl = n0 & 1023;
  const float* bias = (mat == 0) ? bq : (mat == 1) ? bk : bv;
  const short* Wm = Wt + (size_t)mat * (1024 * 768);
  const int tid = threadIdx.x, lane = tid & 63, wave = tid >> 6;
  const int ln = lane & 15, quad = lane >> 4, q8 = quad * 8;
  __shared__ __align__(16) short Bs[2][128][56];  // stride 112B: 16B-aligned, 2-way max
  const int brow = tid >> 1, bseg = (tid & 1) * 16;
  const short* gB = Wm + (size_t)(cl + brow) * DIN + bseg;
  {
    bf16x8 b0 = *(const bf16x8*)(gB);
    bf16x8 b1 = *(const bf16x8*)(gB + 8);
    *(bf16x8*)&Bs[0][brow][bseg] = b0;
    *(bf16x8*)&Bs[0][brow][bseg + 8] = b1;
  }
  bf16x8 cb0 = *(const bf16x8*)(gB + 32);
  bf16x8 cb1 = *(const bf16x8*)(gB + 40);
  __syncthreads();
  f32x4 acc[8];
#pragma unroll
  for (int nt = 0; nt < 8; ++nt) acc[nt] = (f32x4){0.f, 0.f, 0.f, 0.f};
  const short* a0 = xb + (size_t)(i0 + 16 * wave + ln) * DIN + q8;
  for (int ks = 0; ks < 24; ++ks) {
    const int bufc = ks & 1;
    bf16x8 nb0, nb1;
    if (ks < 22) {
      nb0 = *(const bf16x8*)(gB + 32 * (ks + 2));
      nb1 = *(const bf16x8*)(gB + 32 * (ks + 2) + 8);
    }
    bf16x8 A0 = *(const bf16x8*)(a0 + 32 * ks);
#pragma unroll
    for (int nt = 0; nt < 8; ++nt) {
      bf16x8 B = *(const bf16x8*)&Bs[bufc][16 * nt + ln][q8];
      acc[nt] = __builtin_amdgcn_mfma_f32_16x16x32_bf16(A0, B, acc[nt], 0, 0, 0);
    }
    if (ks < 23) {
      *(bf16x8*)&Bs[bufc ^ 1][brow][bseg] = cb0;
      *(bf16x8*)&Bs[bufc ^ 1][brow][bseg + 8] = cb1;
    }
    __syncthreads();
    if (ks < 22) { cb0 = nb0; cb1 = nb1; }
  }
#pragma unroll
  for (int nt = 0; nt < 8; ++nt) {
    int cg = cl + 16 * nt + ln;
    float bb = bias[cg];
#pragma unroll
    for (int reg = 0; reg < 4; ++reg) {
      int rr = i0 + 16 * wave + quad * 4 + reg;
      short s = f2bf(acc[nt][reg] + bb);
      if (mat == 2) {
        Vb[(size_t)rr * 1024 + cg] = s;
      } else {
        int h = cg >> 7, d = cg & 127;
        (mat == 0 ? Qb : Kb)[((size_t)h * NN + rr) * HD + d] = s;
      }
    }
  }
}

// ---------------- fused: gates (bid<2048, shuffle-reduce) | Vb->Vt (bid>=2048) ------
__global__ __launch_bounds__(256) void k_vtg(const short* __restrict__ Qb,
                                             const short* __restrict__ Kb,
                                             const float* __restrict__ gqw,
                                             const float* __restrict__ gqb,
                                             const float* __restrict__ gkw,
                                             const float* __restrict__ gkb,
                                             float* __restrict__ GQ,
                                             float* __restrict__ GK,
                                             const short* __restrict__ Vb,
                                             short* __restrict__ Vt) {
  const int bid = blockIdx.x;
  const int tid = threadIdx.x;
  __shared__ __align__(16) char smem[17408];
  if (bid < 2048) {  // gates
    const int i = bid;
    const int lane = tid & 63, wave = tid >> 6;
    float aq[NH] = {}, ak[NH] = {};
    for (int d = tid; d < DOUT; d += 256) {
      int h = d >> 7, dd = d & 127;
      float qv = bf2f(Qb[((size_t)h * NN + i) * HD + dd]);
      float kv = bf2f(Kb[((size_t)h * NN + i) * HD + dd]);
      float4 ga = *(const float4*)(gqw + (size_t)d * NH);
      float4 gb = *(const float4*)(gqw + (size_t)d * NH + 4);
      float4 ha = *(const float4*)(gkw + (size_t)d * NH);
      float4 hb = *(const float4*)(gkw + (size_t)d * NH + 4);
      aq[0] = fmaf(qv, ga.x, aq[0]); aq[1] = fmaf(qv, ga.y, aq[1]);
      aq[2] = fmaf(qv, ga.z, aq[2]); aq[3] = fmaf(qv, ga.w, aq[3]);
      aq[4] = fmaf(qv, gb.x, aq[4]); aq[5] = fmaf(qv, gb.y, aq[5]);
      aq[6] = fmaf(qv, gb.z, aq[6]); aq[7] = fmaf(qv, gb.w, aq[7]);
      ak[0] = fmaf(kv, ha.x, ak[0]); ak[1] = fmaf(kv, ha.y, ak[1]);
      ak[2] = fmaf(kv, ha.z, ak[2]); ak[3] = fmaf(kv, ha.w, ak[3]);
      ak[4] = fmaf(kv, hb.x, ak[4]); ak[5] = fmaf(kv, hb.y, ak[5]);
      ak[6] = fmaf(kv, hb.z, ak[6]); ak[7] = fmaf(kv, hb.w, ak[7]);
    }
#pragma unroll
    for (int h = 0; h < NH; ++h) {
#pragma unroll
      for (int off = 1; off < 64; off <<= 1) {
        aq[h] += __shfl_xor(aq[h], off);
        ak[h] += __shfl_xor(ak[h], off);
      }
    }
    auto part = (float (*)[16])(smem);  // [4][16]
    if (lane == 0) {
#pragma unroll
      for (int h = 0; h < NH; ++h) {
        part[wave][h] = aq[h];
        part[wave][8 + h] = ak[h];
      }
    }
    __syncthreads();
    if (tid < 16) {
      float s = part[0][tid] + part[1][tid] + part[2][tid] + part[3][tid];
      if (tid < 8) GQ[(size_t)i * NH + tid] = tanhf(s + gqb[tid]);
      else GK[(size_t)i * NH + tid - 8] = tanhf(s + gkb[tid - 8]);
    }
  } else {  // Vb -> Vt[h][d][n]
    auto t = (short (*)[136])(smem);  // [64][136]
    const int w = bid - 2048;
    const int i0 = (w & 31) * 64, h = w >> 5;
#pragma unroll
    for (int l = 0; l < 2; ++l) {
      int f = tid + l * 256;
      int r = f >> 3, c8 = (f & 7) * 16;
      const short* src = Vb + (size_t)(i0 + r) * 1024 + h * HD + c8;
      *(bf16x8*)&t[r][c8] = *(const bf16x8*)src;
      *(bf16x8*)&t[r][c8 + 8] = *(const bf16x8*)(src + 8);
    }
    __syncthreads();
    int d = tid >> 1, half = tid & 1;
    union { short s[32]; float4 f[4]; } buf;
#pragma unroll
    for (int ii = 0; ii < 32; ++ii) buf.s[ii] = t[32 * half + ii][d];
    short* dst = Vt + (size_t)h * (HD * NN) + (size_t)d * NN + i0 + 32 * half;
#pragma unroll
    for (int q = 0; q < 4; ++q) ((float4*)dst)[q] = buf.f[q];
  }
}

// ---------------- fused scores + assemble (R7 main loop + barrier-free epilogue) ----
// Main loop: R7's double-buffered 2-head-ahead LDS pipeline (VGPR 64, proven 101us).
// Epilogue: ALL 8 heads computed into oL8[256][34] f32 (34816B = exact alias of the
// dead Q/K double-buffer; LDS total unchanged at 38400) with ZERO barriers -> the
// per-head motif prefetches are no longer drained by the compiler's vmcnt(0)-before-
// s_barrier (16 drains -> 1). Store phase: one barrier, then 8 full-line passes.
// Stride 34 rows are 8B-aligned -> float4 read as 2x float2 (ds_read_b64 pairs).
__global__ __launch_bounds__(256, 4) void k_sa(const short* __restrict__ Qb,
                                               const short* __restrict__ Kb,
                                               const int* __restrict__ batch,
                                               const float* __restrict__ motif,
                                               const float* __restrict__ GQ,
                                               const float* __restrict__ GK,
                                               const float* __restrict__ Wh,
                                               const float* __restrict__ alpha_p,
                                               const float* __restrict__ beta_p,
                                               float* __restrict__ ATTN) {
  // XCD patch swizzle: 16x16 block patches per XCD
  const unsigned gid = blockIdx.y * gridDim.x + blockIdx.x;
  const unsigned xcd = gid & 7, idx = gid >> 3;
  const unsigned P = xcd + 8 * (idx >> 8);
  const unsigned r256 = idx & 255;
  const unsigned bx = 16 * (P & 3) + (r256 & 15);
  const unsigned by = 16 * (P >> 2) + (r256 >> 4);
  const int i0 = by * 32, j0 = bx * 32;

  const int tid = threadIdx.x, lane = tid & 63, wave = tid >> 6;
  const int wr = wave >> 1, wc = wave & 1;
  const int ln = lane & 15, quad = lane >> 4, q8 = quad * 8;

  __shared__ __align__(16) char smem[38400];
  auto Qs  = (short (*)[32][136])(smem);            // [2][32][136] bf16
  auto Ks  = (short (*)[32][136])(smem + 17408);    // [2][32][136] bf16
  auto oL8 = (float (*)[34])(smem);                 // [256][34] f32 (aliases Qs+Ks)
  auto gqL = (float (*)[12])(smem + 34816);         // [32][12]
  auto gkL = (float (*)[12])(smem + 36352);         // [32][12]
  float* sW = (float*)(smem + 37888);               // [64]

  const int rA = 16 * wr + quad * 4;
  const int cA = 16 * wc + ln;

  const int srow = tid >> 3, sseg = (tid & 7) * 16;
  const short* gQ0 = Qb + (size_t)(i0 + srow) * HD + sseg;
  const short* gK0 = Kb + (size_t)(j0 + srow) * HD + sseg;
  const size_t hstep = (size_t)NN * HD;

  // prologue: stage head0 to LDS, preload head1 into regs
  {
    bf16x8 q0 = *(const bf16x8*)(gQ0);
    bf16x8 q1 = *(const bf16x8*)(gQ0 + 8);
    bf16x8 k0 = *(const bf16x8*)(gK0);
    bf16x8 k1 = *(const bf16x8*)(gK0 + 8);
    *(bf16x8*)&Qs[0][srow][sseg] = q0;
    *(bf16x8*)&Qs[0][srow][sseg + 8] = q1;
    *(bf16x8*)&Ks[0][srow][sseg] = k0;
    *(bf16x8*)&Ks[0][srow][sseg + 8] = k1;
  }
  bf16x8 cq0 = *(const bf16x8*)(gQ0 + hstep);
  bf16x8 cq1 = *(const bf16x8*)(gQ0 + hstep + 8);
  bf16x8 ck0 = *(const bf16x8*)(gK0 + hstep);
  bf16x8 ck1 = *(const bf16x8*)(gK0 + hstep + 8);
  if (tid < 64) {
    const int half = tid >> 5, r = tid & 31;
    const float* src = (half ? GK : GQ) + (size_t)((half ? j0 : i0) + r) * NH;
    float4 a = *(const float4*)src;
    float4 b = *(const float4*)(src + 4);
    float* dst = half ? &gkL[r][0] : &gqL[r][0];
    *(float4*)dst = a;
    *(float4*)(dst + 4) = b;
    sW[tid] = Wh[tid];
  }
  const int4 bi4 = *(const int4*)(batch + i0 + rA);
  const int bj = batch[j0 + cA];
  const float alpha = alpha_p[0], beta = beta_p[0];
  __syncthreads();

  f32x4 accS[NH], accT[NH];
#pragma unroll
  for (int h = 0; h < NH; ++h) {
    accS[h] = (f32x4){0.f, 0.f, 0.f, 0.f};
    accT[h] = (f32x4){0.f, 0.f, 0.f, 0.f};
  }

#pragma unroll
  for (int h = 0; h < NH; ++h) {
    const int bufc = h & 1;
    bf16x8 nq0, nq1, nk0, nk1;
    if (h < 6) {  // issue head h+2's loads (in flight for ~1 full iteration)
      const short* gq_ = gQ0 + (size_t)(h + 2) * hstep;
      const short* gk_ = gK0 + (size_t)(h + 2) * hstep;
      nq0 = *(const bf16x8*)(gq_);
      nq1 = *(const bf16x8*)(gq_ + 8);
      nk0 = *(const bf16x8*)(gk_);
      nk1 = *(const bf16x8*)(gk_ + 8);
    }
#pragma unroll
    for (int ks = 0; ks < 4; ++ks) {
      bf16x8 aS = *(const bf16x8*)&Qs[bufc][16 * wr + ln][ks * 32 + q8];
      bf16x8 bS = *(const bf16x8*)&Ks[bufc][16 * wc + ln][ks * 32 + q8];
      accS[h] = __builtin_amdgcn_mfma_f32_16x16x32_bf16(aS, bS, accS[h], 0, 0, 0);
      bf16x8 aT = *(const bf16x8*)&Ks[bufc][16 * wr + ln][ks * 32 + q8];
      bf16x8 bT = *(const bf16x8*)&Qs[bufc][16 * wc + ln][ks * 32 + q8];
      accT[h] = __builtin_amdgcn_mfma_f32_16x16x32_bf16(aT, bT, accT[h], 0, 0, 0);
    }
    if (h < 7) {  // commit head h+1 (loaded last iteration) to the other buffer
      *(bf16x8*)&Qs[bufc ^ 1][srow][sseg] = cq0;
      *(bf16x8*)&Qs[bufc ^ 1][srow][sseg + 8] = cq1;
      *(bf16x8*)&Ks[bufc ^ 1][srow][sseg] = ck0;
      *(bf16x8*)&Ks[bufc ^ 1][srow][sseg + 8] = ck1;
    }
    __syncthreads();
    if (h < 6) { cq0 = nq0; cq1 = nq1; ck0 = nk0; ck1 = nk1; }
  }
  // (final barrier of h=7 guarantees all Q/K reads done -> oL8 alias safe)

  // mask + scale S
  int okm[4];
  okm[0] = (bi4.x == bj); okm[1] = (bi4.y == bj);
  okm[2] = (bi4.z == bj); okm[3] = (bi4.w == bj);
#pragma unroll
  for (int reg = 0; reg < 4; ++reg)
#pragma unroll
    for (int h = 0; h < NH; ++h)
      accS[h][reg] = okm[reg] ? accS[h][reg] * SCALEF : NEGF;

  // ---- phase 1: compute ALL heads into oL8, zero barriers, motif 2-ahead ----
  union { float4 v; float f[4]; } moc, mon, mo2;
  moc.v = *(const float4*)(motif + ((size_t)(j0 + cA)) * NN + i0 + rA);
  mon.v = *(const float4*)(motif + ((size_t)(NN + j0 + cA)) * NN + i0 + rA);
#pragma unroll
  for (int h = 0; h < NH; ++h) {
    if (h < 6)
      mo2.v = *(const float4*)(motif + ((size_t)(h + 2) * NN + j0 + cA) * NN + i0 + rA);
    float w8[NH];
#pragma unroll
    for (int h2 = 0; h2 < NH; ++h2) w8[h2] = sW[h2 * NH + h];
    const float gkj = gkL[cA][h];
#pragma unroll
    for (int reg = 0; reg < 4; ++reg) {
      float tv = okm[reg] ? accT[h][reg] * SCALEF : NEGF;
      float hm = 0.f;
#pragma unroll
      for (int h2 = 0; h2 < NH; ++h2) hm = fmaf(accS[h2][reg], w8[h2], hm);
      float o = accS[h][reg] * (1.f + gqL[rA + reg][h] + gkj) +
                alpha * tv + beta * moc.f[reg] + hm;
      oL8[h * 32 + rA + reg][cA] = o;
    }
    moc.v = mon.v;
    mon.v = mo2.v;
  }
  __syncthreads();  // the ONLY epilogue barrier

  // ---- phase 2: 8 full-line store passes, no barriers ----
  const int orow = tid >> 3, oslot = (tid & 7) * 4;
#pragma unroll
  for (int h = 0; h < NH; ++h) {
    float2 a = *(const float2*)&oL8[h * 32 + orow][oslot];
    float2 b = *(const float2*)&oL8[h * 32 + orow][oslot + 2];
    float4 ov = float4{a.x, a.y, b.x, b.y};
    *(float4*)(ATTN + ((size_t)h * NN + i0 + orow) * NN + j0 + oslot) = ov;
  }
}

// ---------------- P@V: 16-row strips x 4 j-quarter waves, barrier-free loop --------
__global__ __launch_bounds__(256) void k_pv(const float* __restrict__ ATTN,
                                            const short* __restrict__ Vt,
                                            short* __restrict__ Obf) {
  const int bid = blockIdx.x;      // 0..1023
  const int h = bid & 7;           // head -> XCD (V stays L2-resident)
  const int i0 = (bid >> 3) * 16;  // 128 strips
  const int tid = threadIdx.x, lane = tid & 63, wave = tid >> 6;
  const int ln = lane & 15, quad = lane >> 4, q8 = quad * 8;
  __shared__ float accL[4][16][140];
  __shared__ float SUML[4][16];
  const int jbase = wave * 512;
  const float* arow = ATTN + ((size_t)h * NN + i0 + ln) * NN + jbase;
  const short* vbase = Vt + (size_t)h * (HD * NN) + jbase;
  f32x4 acc[8];
#pragma unroll
  for (int nt = 0; nt < 8; ++nt) acc[nt] = (f32x4){0.f, 0.f, 0.f, 0.f};
  float rowsum = 0.f;
  for (int c = 0; c < 16; ++c) {
    const int jk = c * 32;
    float4 u1 = *(const float4*)(arow + jk + q8);
    float4 u2 = *(const float4*)(arow + jk + q8 + 4);
    float p0 = __expf(u1.x - EXPSHIFT), p1 = __expf(u1.y - EXPSHIFT);
    float p2 = __expf(u1.z - EXPSHIFT), p3 = __expf(u1.w - EXPSHIFT);
    float p4 = __expf(u2.x - EXPSHIFT), p5 = __expf(u2.y - EXPSHIFT);
    float p6 = __expf(u2.z - EXPSHIFT), p7 = __expf(u2.w - EXPSHIFT);
    rowsum += ((p0 + p1) + (p2 + p3)) + ((p4 + p5) + (p6 + p7));
    bf16x8 a;
    a[0] = f2bf(p0); a[1] = f2bf(p1); a[2] = f2bf(p2); a[3] = f2bf(p3);
    a[4] = f2bf(p4); a[5] = f2bf(p5); a[6] = f2bf(p6); a[7] = f2bf(p7);
#pragma unroll
    for (int nt = 0; nt < 8; ++nt) {
      bf16x8 b = *(const bf16x8*)(vbase + (size_t)(16 * nt + ln) * NN + jk + q8);
      acc[nt] = __builtin_amdgcn_mfma_f32_16x16x32_bf16(a, b, acc[nt], 0, 0, 0);
    }
  }
  rowsum += __shfl_xor(rowsum, 16);
  rowsum += __shfl_xor(rowsum, 32);
  if (lane < 16) SUML[wave][ln] = rowsum;
#pragma unroll
  for (int nt = 0; nt < 8; ++nt)
#pragma unroll
    for (int reg = 0; reg < 4; ++reg)
      accL[wave][quad * 4 + reg][16 * nt + ln] = acc[nt][reg];
  __syncthreads();
  const int r = tid >> 4, d0 = (tid & 15) * 8;
  const float inv = 1.0f / (SUML[0][r] + SUML[1][r] + SUML[2][r] + SUML[3][r]);
  union { short s[8]; bf16x8 v; } ob;
#pragma unroll
  for (int e = 0; e < 8; ++e) {
    float s = accL[0][r][d0 + e] + accL[1][r][d0 + e] +
              accL[2][r][d0 + e] + accL[3][r][d0 + e];
    ob.s[e] = f2bf(s * inv);
  }
  *(bf16x8*)(Obf + (size_t)(i0 + r) * DOUT + h * HD + d0) = ob.v;
}

// ---------------- out-proj: 64x64 tiles, LDS-staged B panel ----------------
__global__ __launch_bounds__(256) void k_outproj(const short* __restrict__ Obf,
                                                 const short* __restrict__ wot,
                                                 float* __restrict__ YACC) {
  const int n0 = blockIdx.x * 64;   // 768 cols -> 12
  const int i0 = blockIdx.y * 64;   // 2048 rows -> 32
  const int tid = threadIdx.x, lane = tid & 63, wave = tid >> 6;
  const int ln = lane & 15, quad = lane >> 4, q8 = quad * 8;
  __shared__ __align__(16) short Bs[2][64][56];
  const int brow = tid >> 2, bseg = (tid & 3) * 8;  // 64 rows x 4 segs of 16B
  const short* gB = wot + (size_t)(n0 + brow) * DOUT + bseg;
  {
    bf16x8 b0 = *(const bf16x8*)(gB);
    *(bf16x8*)&Bs[0][brow][bseg] = b0;
  }
  bf16x8 cb0 = *(const bf16x8*)(gB + 32);
  __syncthreads();
  f32x4 acc[4];
#pragma unroll
  for (int nt = 0; nt < 4; ++nt) acc[nt] = (f32x4){0.f, 0.f, 0.f, 0.f};
  const short* a0 = Obf + (size_t)(i0 + 16 * wave + ln) * DOUT + q8;
  for (int ks = 0; ks < 32; ++ks) {
    const int bufc = ks & 1;
    bf16x8 nb0;
    if (ks < 30) nb0 = *(const bf16x8*)(gB + 32 * (ks + 2));
    bf16x8 A0 = *(const bf16x8*)(a0 + 32 * ks);
#pragma unroll
    for (int nt = 0; nt < 4; ++nt) {
      bf16x8 B = *(const bf16x8*)&Bs[bufc][16 * nt + ln][q8];
      acc[nt] = __builtin_amdgcn_mfma_f32_16x16x32_bf16(A0, B, acc[nt], 0, 0, 0);
    }
    if (ks < 31) *(bf16x8*)&Bs[bufc ^ 1][brow][bseg] = cb0;
    __syncthreads();
    if (ks < 30) cb0 = nb0;
  }
#pragma unroll
  for (int nt = 0; nt < 4; ++nt) {
    int cg = n0 + 16 * nt + ln;
#pragma unroll
    for (int reg = 0; reg < 4; ++reg) {
      int rr = i0 + 16 * wave + quad * 4 + reg;
      YACC[(size_t)rr * DIN + cg] = acc[nt][reg];
    }
  }
}

// ---------------- bias + residual + LayerNorm (shuffle-reduce, 2 barriers) --------
__global__ __launch_bounds__(256) void k_ln(const float* __restrict__ YACC,
                                            const float* __restrict__ x,
                                            const float* __restrict__ wo_b,
                                            const float* __restrict__ g,
                                            const float* __restrict__ b,
                                            float* __restrict__ y) {
  const int i = blockIdx.x;
  const int tid = threadIdx.x;
  const int lane = tid & 63, wave = tid >> 6;
  float v[3];
#pragma unroll
  for (int t = 0; t < 3; ++t) {
    int cc = tid + t * 256;
    v[t] = YACC[(size_t)i * DIN + cc] + wo_b[cc] + x[(size_t)i * DIN + cc];
  }
  __shared__ float p1[4], p2[4];
  float s = v[0] + v[1] + v[2];
#pragma unroll
  for (int off = 1; off < 64; off <<= 1) s += __shfl_xor(s, off);
  if (lane == 0) p1[wave] = s;
  __syncthreads();
  const float mu = (p1[0] + p1[1] + p1[2] + p1[3]) * (1.0f / DIN);
  float q = 0.f;
#pragma unroll
  for (int t = 0; t < 3; ++t) {
    float d = v[t] - mu;
    q += d * d;
  }
#pragma unroll
  for (int off = 1; off < 64; off <<= 1) q += __shfl_xor(q, off);
  if (lane == 0) p2[wave] = q;
  __syncthreads();
  const float rs = rsqrtf((p2[0] + p2[1] + p2[2] + p2[3]) * (1.0f / DIN) + EPSF);
#pragma unroll
  for (int t = 0; t < 3; ++t) {
    int cc = tid + t * 256;
    y[(size_t)i * DIN + cc] = (v[t] - mu) * rs * g[cc] + b[cc];
  }
}

extern "C" void kernel_launch(void* const* d_in, const int* in_sizes, int n_in,
                              void* d_out, int out_size, void* d_ws, size_t ws_size,
                              hipStream_t stream) {
  (void)in_sizes; (void)n_in; (void)out_size; (void)ws_size;
  const float* x       = (const float*)d_in[0];
  const int*   batch   = (const int*)d_in[1];
  const float* motif   = (const float*)d_in[2];
  const float* wq_w    = (const float*)d_in[3];
  const float* wq_b    = (const float*)d_in[4];
  const float* wk_w    = (const float*)d_in[5];
  const float* wk_b    = (const float*)d_in[6];
  const float* wv_w    = (const float*)d_in[7];
  const float* wv_b    = (const float*)d_in[8];
  const float* wo_w    = (const float*)d_in[9];
  const float* wo_b    = (const float*)d_in[10];
  const float* ln_g    = (const float*)d_in[11];
  const float* ln_b    = (const float*)d_in[12];
  const float* alpha_p = (const float*)d_in[13];
  const float* beta_p  = (const float*)d_in[14];
  const float* gq_w    = (const float*)d_in[15];
  const float* gq_b    = (const float*)d_in[16];
  const float* gk_w    = (const float*)d_in[17];
  const float* gk_b    = (const float*)d_in[18];
  const float* headW   = (const float*)d_in[19];

  float* y    = (float*)d_out;
  float* ATTN = (float*)d_out + (size_t)NN * DIN;
  float* ws   = (float*)d_ws;
  short* Obf  = (short*)(ws + OFF_OBF);
  short* wot  = (short*)(ws + OFF_WOT);
  float* YACC = ws + OFF_YACC;
  short* Qb   = (short*)(ws + OFF_Q);
  short* Kb   = (short*)(ws + OFF_K);
  short* Vb   = (short*)(ws + OFF_VB);
  short* Vt   = (short*)(ws + OFF_VT);
  short* xb   = (short*)(ws + OFF_XB);
  short* Wt   = (short*)(ws + OFF_WT);
  float* GQ   = ws + OFF_GQ;
  float* GK   = ws + OFF_GK;

  k_prep<<<2304, 256, 0, stream>>>(x, xb, wq_w, wk_w, wv_w, Wt, wo_w, wot);
  k_qkv<<<dim3(24, 32), 256, 0, stream>>>(xb, Wt, wq_b, wk_b, wv_b, Qb, Kb, Vb);
  k_vtg<<<2304, 256, 0, stream>>>(Qb, Kb, gq_w, gq_b, gk_w, gk_b, GQ, GK, Vb, Vt);
  k_sa<<<dim3(64, 64), 256, 0, stream>>>(Qb, Kb, batch, motif, GQ, GK, headW,
                                         alpha_p, beta_p, ATTN);
  k_pv<<<1024, 256, 0, stream>>>(ATTN, Vt, Obf);
  k_outproj<<<dim3(12, 32), 256, 0, stream>>>(Obf, wot, YACC);
  k_ln<<<NN, 256, 0, stream>>>(YACC, x, wo_b, ln_g, ln_b, y);
}

// Round 10
// 453.816 us; speedup vs baseline: 1.1306x; 1.0027x over previous
//
#include <hip/hip_runtime.h>

#define NN    2048
#define DIN   768
#define DOUT  1024
#define NH    8
#define HD    128
#define SCALEF 0.08838834764831845f
#define NEGF  (-1.0e9f)
#define EPSF  1e-5f
#define EXPSHIFT 16.0f

typedef __attribute__((ext_vector_type(4))) float f32x4;
typedef __attribute__((ext_vector_type(8))) short bf16x8;

// workspace layout (float-slot offsets)
#define OFF_OBF  0                         // bf16 O [2048][1024]
#define OFF_WOT  1048576                   // bf16 wo^T [768][1024]
#define OFF_YACC 1441792                   // f32 [2048][768]
#define OFF_Q    3686400                   // bf16 [8][2048][128]
#define OFF_K    4734976
#define OFF_VB   5783552                   // bf16 [2048][1024]
#define OFF_VT   6832128                   // bf16 [8][128][2048]
#define OFF_XB   7880704                   // bf16 [2048][768]
#define OFF_WT   8667136                   // bf16 [3][1024][768]
#define OFF_GQ   9846784
#define OFF_GK   9863168

__device__ __forceinline__ short f2bf(float f) {
  union { float f; unsigned u; } v; v.f = f;
  unsigned r = v.u + 0x7FFF + ((v.u >> 16) & 1);
  return (short)(r >> 16);
}
__device__ __forceinline__ float bf2f(short s) {
  union { unsigned u; float f; } v; v.u = ((unsigned)(unsigned short)s) << 16;
  return v.f;
}

// ---------------- fused preprocessing: cast_x | w_cast_t | wo_t ----------------
__global__ __launch_bounds__(256) void k_prep(const float* __restrict__ x,
                                              short* __restrict__ xb,
                                              const float* __restrict__ wq,
                                              const float* __restrict__ wk,
                                              const float* __restrict__ wv,
                                              short* __restrict__ Wt,
                                              const float* __restrict__ wo,
                                              short* __restrict__ wot) {
  const int bid = blockIdx.x;
  const int tid = threadIdx.x;
  if (bid < 1536) {  // cast x -> bf16
    int idx = bid * 256 + tid;
    float4 v = ((const float4*)x)[idx];
    union { short s[4]; float2 f; } u;
    u.s[0] = f2bf(v.x); u.s[1] = f2bf(v.y); u.s[2] = f2bf(v.z); u.s[3] = f2bf(v.w);
    ((float2*)xb)[idx] = u.f;
    return;
  }
  __shared__ float t[64][65];
  if (bid < 2112) {  // W[768][1024] -> Wt[z][1024][768] bf16
    const int w = bid - 1536;
    const int z = w / 192, rem = w % 192;
    const int c0 = (rem % 16) * 64, k0 = (rem / 16) * 64;
    const float* Wm = (z == 0) ? wq : (z == 1) ? wk : wv;
#pragma unroll
    for (int l = 0; l < 4; ++l) {
      int f = tid + l * 256;
      int r = f >> 4, c4 = (f & 15) * 4;
      *(float4*)&t[r][c4] = *(const float4*)(Wm + (size_t)(k0 + r) * DOUT + c0 + c4);
    }
    __syncthreads();
    int r2 = tid >> 2, q = tid & 3;
    union { short s[16]; float4 f[2]; } buf;
#pragma unroll
    for (int jj = 0; jj < 16; ++jj) buf.s[jj] = f2bf(t[q * 16 + jj][r2]);
    short* dst = Wt + (size_t)z * (1024 * 768) + (size_t)(c0 + r2) * 768 + k0 + q * 16;
    ((float4*)dst)[0] = buf.f[0];
    ((float4*)dst)[1] = buf.f[1];
  } else {  // wo[1024][768] -> wot[768][1024] bf16
    const int w = bid - 2112;
    const int c0 = (w % 12) * 64, k0 = (w / 12) * 64;
#pragma unroll
    for (int l = 0; l < 4; ++l) {
      int f = tid + l * 256;
      int r = f >> 4, c4 = (f & 15) * 4;
      *(float4*)&t[r][c4] = *(const float4*)(wo + (size_t)(k0 + r) * DIN + c0 + c4);
    }
    __syncthreads();
    int r2 = tid >> 2, q = tid & 3;
    union { short s[16]; float4 f[2]; } buf;
#pragma unroll
    for (int jj = 0; jj < 16; ++jj) buf.s[jj] = f2bf(t[q * 16 + jj][r2]);
    short* dst = wot + (size_t)(c0 + r2) * DOUT + k0 + q * 16;
    ((float4*)dst)[0] = buf.f[0];
    ((float4*)dst)[1] = buf.f[1];
  }
}

// ---------------- QKV projection: 64x128 tiles, LDS-staged B panel ----------------
__global__ __launch_bounds__(256) void k_qkv(const short* __restrict__ xb,
                                             const short* __restrict__ Wt,
                                             const float* __restrict__ bq,
                                             const float* __restrict__ bk,
                                             const float* __restrict__ bv,
                                             short* __restrict__ Qb,
                                             short* __restrict__ Kb,
                                             short* __restrict__ Vb) {
  const int n0 = blockIdx.x * 128;  // 0..2944 over 3072
  const int i0 = blockIdx.y * 64;   // 0..1984
  const int mat = n0 >> 10;
  const int cl = n0 & 1023;
  const float* bias = (mat == 0) ? bq : (mat == 1) ? bk : bv;
  const short* Wm = Wt + (size_t)mat * (1024 * 768);
  const int tid = threadIdx.x, lane = tid & 63, wave = tid >> 6;
  const int ln = lane & 15, quad = lane >> 4, q8 = quad * 8;
  __shared__ __align__(16) short Bs[2][128][56];  // stride 112B: 16B-aligned, 2-way max
  const int brow = tid >> 1, bseg = (tid & 1) * 16;
  const short* gB = Wm + (size_t)(cl + brow) * DIN + bseg;
  {
    bf16x8 b0 = *(const bf16x8*)(gB);
    bf16x8 b1 = *(const bf16x8*)(gB + 8);
    *(bf16x8*)&Bs[0][brow][bseg] = b0;
    *(bf16x8*)&Bs[0][brow][bseg + 8] = b1;
  }
  bf16x8 cb0 = *(const bf16x8*)(gB + 32);
  bf16x8 cb1 = *(const bf16x8*)(gB + 40);
  __syncthreads();
  f32x4 acc[8];
#pragma unroll
  for (int nt = 0; nt < 8; ++nt) acc[nt] = (f32x4){0.f, 0.f, 0.f, 0.f};
  const short* a0 = xb + (size_t)(i0 + 16 * wave + ln) * DIN + q8;
  for (int ks = 0; ks < 24; ++ks) {
    const int bufc = ks & 1;
    bf16x8 nb0, nb1;
    if (ks < 22) {
      nb0 = *(const bf16x8*)(gB + 32 * (ks + 2));
      nb1 = *(const bf16x8*)(gB + 32 * (ks + 2) + 8);
    }
    bf16x8 A0 = *(const bf16x8*)(a0 + 32 * ks);
#pragma unroll
    for (int nt = 0; nt < 8; ++nt) {
      bf16x8 B = *(const bf16x8*)&Bs[bufc][16 * nt + ln][q8];
      acc[nt] = __builtin_amdgcn_mfma_f32_16x16x32_bf16(A0, B, acc[nt], 0, 0, 0);
    }
    if (ks < 23) {
      *(bf16x8*)&Bs[bufc ^ 1][brow][bseg] = cb0;
      *(bf16x8*)&Bs[bufc ^ 1][brow][bseg + 8] = cb1;
    }
    __syncthreads();
    if (ks < 22) { cb0 = nb0; cb1 = nb1; }
  }
#pragma unroll
  for (int nt = 0; nt < 8; ++nt) {
    int cg = cl + 16 * nt + ln;
    float bb = bias[cg];
#pragma unroll
    for (int reg = 0; reg < 4; ++reg) {
      int rr = i0 + 16 * wave + quad * 4 + reg;
      short s = f2bf(acc[nt][reg] + bb);
      if (mat == 2) {
        Vb[(size_t)rr * 1024 + cg] = s;
      } else {
        int h = cg >> 7, d = cg & 127;
        (mat == 0 ? Qb : Kb)[((size_t)h * NN + rr) * HD + d] = s;
      }
    }
  }
}

// ---------------- fused: gates via MFMA (bid<128) | Vb->Vt (bid>=128) ------
// Gates = [2048x1024]@[1024x8] x2 GEMV. Old version re-read 64KB of weights per
// row-block (134MB L2 total). New: 128 blocks x 16 rows; B^T staged in LDS bf16
// ONCE per block (weight traffic /16); 4-wave K-split (256 K each); one barrier;
// cross-wave combine + tanh by 256 threads.
__global__ __launch_bounds__(256) void k_vtg(const short* __restrict__ Qb,
                                             const short* __restrict__ Kb,
                                             const float* __restrict__ gqw,
                                             const float* __restrict__ gqb,
                                             const float* __restrict__ gkw,
                                             const float* __restrict__ gkb,
                                             float* __restrict__ GQ,
                                             float* __restrict__ GK,
                                             const short* __restrict__ Vb,
                                             short* __restrict__ Vt) {
  const int bid = blockIdx.x;
  const int tid = threadIdx.x;
  __shared__ __align__(16) char smem[41216];
  if (bid < 128) {  // gates
    const int i0 = bid * 16;
    const int lane = tid & 63, wave = tid >> 6;
    const int ln = lane & 15, quad = lane >> 4, q8 = quad * 8;
    auto BqT = (short (*)[1032])(smem);             // [8][1032] bf16
    auto BkT = (short (*)[1032])(smem + 16512);     // [8][1032] bf16
    auto pQ  = (float (*)[16][16])(smem + 33024);   // [4][16][16]
    auto pK  = (float (*)[16][16])(smem + 37120);   // [4][16][16]
    // build B^T (bf16): thread covers k = tid*4 .. +3
#pragma unroll
    for (int e = 0; e < 4; ++e) {
      const int k = tid * 4 + e;
      float4 a = *(const float4*)(gqw + (size_t)k * NH);
      float4 b = *(const float4*)(gqw + (size_t)k * NH + 4);
      BqT[0][k] = f2bf(a.x); BqT[1][k] = f2bf(a.y);
      BqT[2][k] = f2bf(a.z); BqT[3][k] = f2bf(a.w);
      BqT[4][k] = f2bf(b.x); BqT[5][k] = f2bf(b.y);
      BqT[6][k] = f2bf(b.z); BqT[7][k] = f2bf(b.w);
      float4 c = *(const float4*)(gkw + (size_t)k * NH);
      float4 d = *(const float4*)(gkw + (size_t)k * NH + 4);
      BkT[0][k] = f2bf(c.x); BkT[1][k] = f2bf(c.y);
      BkT[2][k] = f2bf(c.z); BkT[3][k] = f2bf(c.w);
      BkT[4][k] = f2bf(d.x); BkT[5][k] = f2bf(d.y);
      BkT[6][k] = f2bf(d.z); BkT[7][k] = f2bf(d.w);
    }
    __syncthreads();
    // K-split: wave covers k in [256*wave, 256*wave+256), 8 chunks of 32
    f32x4 aq = (f32x4){0.f, 0.f, 0.f, 0.f};
    f32x4 ak = (f32x4){0.f, 0.f, 0.f, 0.f};
    const int lnb = ln & 7;  // B row (cols 8-15 duplicate row 0-7, outputs unused)
#pragma unroll
    for (int c = 0; c < 8; ++c) {
      const int k0 = wave * 256 + c * 32;
      const int h = k0 >> 7, dd = (k0 & 127) + q8;
      bf16x8 Aq = *(const bf16x8*)(Qb + ((size_t)h * NN + i0 + ln) * HD + dd);
      bf16x8 Bq = *(const bf16x8*)&BqT[lnb][k0 + q8];
      aq = __builtin_amdgcn_mfma_f32_16x16x32_bf16(Aq, Bq, aq, 0, 0, 0);
      bf16x8 Ak = *(const bf16x8*)(Kb + ((size_t)h * NN + i0 + ln) * HD + dd);
      bf16x8 Bk = *(const bf16x8*)&BkT[lnb][k0 + q8];
      ak = __builtin_amdgcn_mfma_f32_16x16x32_bf16(Ak, Bk, ak, 0, 0, 0);
    }
#pragma unroll
    for (int reg = 0; reg < 4; ++reg) {
      pQ[wave][quad * 4 + reg][ln] = aq[reg];
      pK[wave][quad * 4 + reg][ln] = ak[reg];
    }
    __syncthreads();
    const int row = tid >> 4, col = tid & 15;
    if (col < NH) {
      float sq = pQ[0][row][col] + pQ[1][row][col] + pQ[2][row][col] + pQ[3][row][col];
      GQ[(size_t)(i0 + row) * NH + col] = tanhf(sq + gqb[col]);
      float sk = pK[0][row][col] + pK[1][row][col] + pK[2][row][col] + pK[3][row][col];
      GK[(size_t)(i0 + row) * NH + col] = tanhf(sk + gkb[col]);
    }
  } else {  // Vb -> Vt[h][d][n]
    auto t = (short (*)[136])(smem);  // [64][136]
    const int w = bid - 128;
    const int i0 = (w & 31) * 64, h = w >> 5;
#pragma unroll
    for (int l = 0; l < 2; ++l) {
      int f = tid + l * 256;
      int r = f >> 3, c8 = (f & 7) * 16;
      const short* src = Vb + (size_t)(i0 + r) * 1024 + h * HD + c8;
      *(bf16x8*)&t[r][c8] = *(const bf16x8*)src;
      *(bf16x8*)&t[r][c8 + 8] = *(const bf16x8*)(src + 8);
    }
    __syncthreads();
    int d = tid >> 1, half = tid & 1;
    union { short s[32]; float4 f[4]; } buf;
#pragma unroll
    for (int ii = 0; ii < 32; ++ii) buf.s[ii] = t[32 * half + ii][d];
    short* dst = Vt + (size_t)h * (HD * NN) + (size_t)d * NN + i0 + 32 * half;
#pragma unroll
    for (int q = 0; q < 4; ++q) ((float4*)dst)[q] = buf.f[q];
  }
}

// ---------------- fused scores + assemble (R9: dbuf main loop + 1-barrier epilogue) --
__global__ __launch_bounds__(256, 4) void k_sa(const short* __restrict__ Qb,
                                               const short* __restrict__ Kb,
                                               const int* __restrict__ batch,
                                               const float* __restrict__ motif,
                                               const float* __restrict__ GQ,
                                               const float* __restrict__ GK,
                                               const float* __restrict__ Wh,
                                               const float* __restrict__ alpha_p,
                                               const float* __restrict__ beta_p,
                                               float* __restrict__ ATTN) {
  // XCD patch swizzle: 16x16 block patches per XCD
  const unsigned gid = blockIdx.y * gridDim.x + blockIdx.x;
  const unsigned xcd = gid & 7, idx = gid >> 3;
  const unsigned P = xcd + 8 * (idx >> 8);
  const unsigned r256 = idx & 255;
  const unsigned bx = 16 * (P & 3) + (r256 & 15);
  const unsigned by = 16 * (P >> 2) + (r256 >> 4);
  const int i0 = by * 32, j0 = bx * 32;

  const int tid = threadIdx.x, lane = tid & 63, wave = tid >> 6;
  const int wr = wave >> 1, wc = wave & 1;
  const int ln = lane & 15, quad = lane >> 4, q8 = quad * 8;

  __shared__ __align__(16) char smem[38400];
  auto Qs  = (short (*)[32][136])(smem);            // [2][32][136] bf16
  auto Ks  = (short (*)[32][136])(smem + 17408);    // [2][32][136] bf16
  auto oL8 = (float (*)[34])(smem);                 // [256][34] f32 (aliases Qs+Ks)
  auto gqL = (float (*)[12])(smem + 34816);         // [32][12]
  auto gkL = (float (*)[12])(smem + 36352);         // [32][12]
  float* sW = (float*)(smem + 37888);               // [64]

  const int rA = 16 * wr + quad * 4;
  const int cA = 16 * wc + ln;

  const int srow = tid >> 3, sseg = (tid & 7) * 16;
  const short* gQ0 = Qb + (size_t)(i0 + srow) * HD + sseg;
  const short* gK0 = Kb + (size_t)(j0 + srow) * HD + sseg;
  const size_t hstep = (size_t)NN * HD;

  // prologue: stage head0 to LDS, preload head1 into regs
  {
    bf16x8 q0 = *(const bf16x8*)(gQ0);
    bf16x8 q1 = *(const bf16x8*)(gQ0 + 8);
    bf16x8 k0 = *(const bf16x8*)(gK0);
    bf16x8 k1 = *(const bf16x8*)(gK0 + 8);
    *(bf16x8*)&Qs[0][srow][sseg] = q0;
    *(bf16x8*)&Qs[0][srow][sseg + 8] = q1;
    *(bf16x8*)&Ks[0][srow][sseg] = k0;
    *(bf16x8*)&Ks[0][srow][sseg + 8] = k1;
  }
  bf16x8 cq0 = *(const bf16x8*)(gQ0 + hstep);
  bf16x8 cq1 = *(const bf16x8*)(gQ0 + hstep + 8);
  bf16x8 ck0 = *(const bf16x8*)(gK0 + hstep);
  bf16x8 ck1 = *(const bf16x8*)(gK0 + hstep + 8);
  if (tid < 64) {
    const int half = tid >> 5, r = tid & 31;
    const float* src = (half ? GK : GQ) + (size_t)((half ? j0 : i0) + r) * NH;
    float4 a = *(const float4*)src;
    float4 b = *(const float4*)(src + 4);
    float* dst = half ? &gkL[r][0] : &gqL[r][0];
    *(float4*)dst = a;
    *(float4*)(dst + 4) = b;
    sW[tid] = Wh[tid];
  }
  const int4 bi4 = *(const int4*)(batch + i0 + rA);
  const int bj = batch[j0 + cA];
  const float alpha = alpha_p[0], beta = beta_p[0];
  __syncthreads();

  f32x4 accS[NH], accT[NH];
#pragma unroll
  for (int h = 0; h < NH; ++h) {
    accS[h] = (f32x4){0.f, 0.f, 0.f, 0.f};
    accT[h] = (f32x4){0.f, 0.f, 0.f, 0.f};
  }

#pragma unroll
  for (int h = 0; h < NH; ++h) {
    const int bufc = h & 1;
    bf16x8 nq0, nq1, nk0, nk1;
    if (h < 6) {  // issue head h+2's loads (in flight for ~1 full iteration)
      const short* gq_ = gQ0 + (size_t)(h + 2) * hstep;
      const short* gk_ = gK0 + (size_t)(h + 2) * hstep;
      nq0 = *(const bf16x8*)(gq_);
      nq1 = *(const bf16x8*)(gq_ + 8);
      nk0 = *(const bf16x8*)(gk_);
      nk1 = *(const bf16x8*)(gk_ + 8);
    }
#pragma unroll
    for (int ks = 0; ks < 4; ++ks) {
      bf16x8 aS = *(const bf16x8*)&Qs[bufc][16 * wr + ln][ks * 32 + q8];
      bf16x8 bS = *(const bf16x8*)&Ks[bufc][16 * wc + ln][ks * 32 + q8];
      accS[h] = __builtin_amdgcn_mfma_f32_16x16x32_bf16(aS, bS, accS[h], 0, 0, 0);
      bf16x8 aT = *(const bf16x8*)&Ks[bufc][16 * wr + ln][ks * 32 + q8];
      bf16x8 bT = *(const bf16x8*)&Qs[bufc][16 * wc + ln][ks * 32 + q8];
      accT[h] = __builtin_amdgcn_mfma_f32_16x16x32_bf16(aT, bT, accT[h], 0, 0, 0);
    }
    if (h < 7) {  // commit head h+1 (loaded last iteration) to the other buffer
      *(bf16x8*)&Qs[bufc ^ 1][srow][sseg] = cq0;
      *(bf16x8*)&Qs[bufc ^ 1][srow][sseg + 8] = cq1;
      *(bf16x8*)&Ks[bufc ^ 1][srow][sseg] = ck0;
      *(bf16x8*)&Ks[bufc ^ 1][srow][sseg + 8] = ck1;
    }
    __syncthreads();
    if (h < 6) { cq0 = nq0; cq1 = nq1; ck0 = nk0; ck1 = nk1; }
  }
  // (final barrier of h=7 guarantees all Q/K reads done -> oL8 alias safe)

  // mask + scale S
  int okm[4];
  okm[0] = (bi4.x == bj); okm[1] = (bi4.y == bj);
  okm[2] = (bi4.z == bj); okm[3] = (bi4.w == bj);
#pragma unroll
  for (int reg = 0; reg < 4; ++reg)
#pragma unroll
    for (int h = 0; h < NH; ++h)
      accS[h][reg] = okm[reg] ? accS[h][reg] * SCALEF : NEGF;

  // ---- phase 1: compute ALL heads into oL8, zero barriers, motif 2-ahead ----
  union { float4 v; float f[4]; } moc, mon, mo2;
  moc.v = *(const float4*)(motif + ((size_t)(j0 + cA)) * NN + i0 + rA);
  mon.v = *(const float4*)(motif + ((size_t)(NN + j0 + cA)) * NN + i0 + rA);
#pragma unroll
  for (int h = 0; h < NH; ++h) {
    if (h < 6)
      mo2.v = *(const float4*)(motif + ((size_t)(h + 2) * NN + j0 + cA) * NN + i0 + rA);
    float w8[NH];
#pragma unroll
    for (int h2 = 0; h2 < NH; ++h2) w8[h2] = sW[h2 * NH + h];
    const float gkj = gkL[cA][h];
#pragma unroll
    for (int reg = 0; reg < 4; ++reg) {
      float tv = okm[reg] ? accT[h][reg] * SCALEF : NEGF;
      float hm = 0.f;
#pragma unroll
      for (int h2 = 0; h2 < NH; ++h2) hm = fmaf(accS[h2][reg], w8[h2], hm);
      float o = accS[h][reg] * (1.f + gqL[rA + reg][h] + gkj) +
                alpha * tv + beta * moc.f[reg] + hm;
      oL8[h * 32 + rA + reg][cA] = o;
    }
    moc.v = mon.v;
    mon.v = mo2.v;
  }
  __syncthreads();  // the ONLY epilogue barrier

  // ---- phase 2: 8 full-line store passes, no barriers ----
  const int orow = tid >> 3, oslot = (tid & 7) * 4;
#pragma unroll
  for (int h = 0; h < NH; ++h) {
    float2 a = *(const float2*)&oL8[h * 32 + orow][oslot];
    float2 b = *(const float2*)&oL8[h * 32 + orow][oslot + 2];
    float4 ov = float4{a.x, a.y, b.x, b.y};
    *(float4*)(ATTN + ((size_t)h * NN + i0 + orow) * NN + j0 + oslot) = ov;
  }
}

// ---------------- P@V: 16-row strips x 4 j-quarter waves, reg-prefetched V --------
__global__ __launch_bounds__(256, 4) void k_pv(const float* __restrict__ ATTN,
                                               const short* __restrict__ Vt,
                                               short* __restrict__ Obf) {
  const int bid = blockIdx.x;      // 0..1023
  const int h = bid & 7;           // head -> XCD (V stays L2-resident)
  const int i0 = (bid >> 3) * 16;  // 128 strips
  const int tid = threadIdx.x, lane = tid & 63, wave = tid >> 6;
  const int ln = lane & 15, quad = lane >> 4, q8 = quad * 8;
  __shared__ float accL[4][16][140];
  __shared__ float SUML[4][16];
  const int jbase = wave * 512;
  const float* arow = ATTN + ((size_t)h * NN + i0 + ln) * NN + jbase;
  const short* vbase = Vt + (size_t)h * (HD * NN) + jbase;
  f32x4 acc[8];
#pragma unroll
  for (int nt = 0; nt < 8; ++nt) acc[nt] = (f32x4){0.f, 0.f, 0.f, 0.f};
  float rowsum = 0.f;
  // prologue: chunk 0's V fragments + ATTN into regs
  bf16x8 vc[8];
#pragma unroll
  for (int nt = 0; nt < 8; ++nt)
    vc[nt] = *(const bf16x8*)(vbase + (size_t)(16 * nt + ln) * NN + q8);
  float4 u1 = *(const float4*)(arow + q8);
  float4 u2 = *(const float4*)(arow + q8 + 4);
#pragma unroll
  for (int c = 0; c < 16; ++c) {
    const int jk = c * 32;
    bf16x8 vn[8];
    float4 n1, n2;
    if (c < 15) {  // issue next chunk's loads FIRST (hide under exp+MFMA)
#pragma unroll
      for (int nt = 0; nt < 8; ++nt)
        vn[nt] = *(const bf16x8*)(vbase + (size_t)(16 * nt + ln) * NN + jk + 32 + q8);
      n1 = *(const float4*)(arow + jk + 32 + q8);
      n2 = *(const float4*)(arow + jk + 32 + q8 + 4);
    }
    float p0 = __expf(u1.x - EXPSHIFT), p1 = __expf(u1.y - EXPSHIFT);
    float p2 = __expf(u1.z - EXPSHIFT), p3 = __expf(u1.w - EXPSHIFT);
    float p4 = __expf(u2.x - EXPSHIFT), p5 = __expf(u2.y - EXPSHIFT);
    float p6 = __expf(u2.z - EXPSHIFT), p7 = __expf(u2.w - EXPSHIFT);
    rowsum += ((p0 + p1) + (p2 + p3)) + ((p4 + p5) + (p6 + p7));
    bf16x8 a;
    a[0] = f2bf(p0); a[1] = f2bf(p1); a[2] = f2bf(p2); a[3] = f2bf(p3);
    a[4] = f2bf(p4); a[5] = f2bf(p5); a[6] = f2bf(p6); a[7] = f2bf(p7);
#pragma unroll
    for (int nt = 0; nt < 8; ++nt)
      acc[nt] = __builtin_amdgcn_mfma_f32_16x16x32_bf16(a, vc[nt], acc[nt], 0, 0, 0);
    if (c < 15) {
#pragma unroll
      for (int nt = 0; nt < 8; ++nt) vc[nt] = vn[nt];
      u1 = n1; u2 = n2;
    }
  }
  rowsum += __shfl_xor(rowsum, 16);
  rowsum += __shfl_xor(rowsum, 32);
  if (lane < 16) SUML[wave][ln] = rowsum;
#pragma unroll
  for (int nt = 0; nt < 8; ++nt)
#pragma unroll
    for (int reg = 0; reg < 4; ++reg)
      accL[wave][quad * 4 + reg][16 * nt + ln] = acc[nt][reg];
  __syncthreads();
  const int r = tid >> 4, d0 = (tid & 15) * 8;
  const float inv = 1.0f / (SUML[0][r] + SUML[1][r] + SUML[2][r] + SUML[3][r]);
  union { short s[8]; bf16x8 v; } ob;
#pragma unroll
  for (int e = 0; e < 8; ++e) {
    float s = accL[0][r][d0 + e] + accL[1][r][d0 + e] +
              accL[2][r][d0 + e] + accL[3][r][d0 + e];
    ob.s[e] = f2bf(s * inv);
  }
  *(bf16x8*)(Obf + (size_t)(i0 + r) * DOUT + h * HD + d0) = ob.v;
}

// ---------------- out-proj: 32x64 tiles (768 blocks, 3/CU), LDS-staged B panel -----
__global__ __launch_bounds__(256) void k_outproj(const short* __restrict__ Obf,
                                                 const short* __restrict__ wot,
                                                 float* __restrict__ YACC) {
  const int n0 = blockIdx.x * 64;   // 768 cols -> 12
  const int i0 = blockIdx.y * 32;   // 2048 rows -> 64
  const int tid = threadIdx.x, lane = tid & 63, wave = tid >> 6;
  const int ln = lane & 15, quad = lane >> 4, q8 = quad * 8;
  const int wr = wave & 1, wcol = wave >> 1;  // rows 16*wr, cols 32*wcol
  __shared__ __align__(16) short Bs[2][64][56];
  const int brow = tid >> 2, bseg = (tid & 3) * 8;  // 64 rows x 4 segs of 16B
  const short* gB = wot + (size_t)(n0 + brow) * DOUT + bseg;
  {
    bf16x8 b0 = *(const bf16x8*)(gB);
    *(bf16x8*)&Bs[0][brow][bseg] = b0;
  }
  bf16x8 cb0 = *(const bf16x8*)(gB + 32);
  __syncthreads();
  f32x4 acc[2];
#pragma unroll
  for (int nt = 0; nt < 2; ++nt) acc[nt] = (f32x4){0.f, 0.f, 0.f, 0.f};
  const short* a0 = Obf + (size_t)(i0 + 16 * wr + ln) * DOUT + q8;
  for (int ks = 0; ks < 32; ++ks) {
    const int bufc = ks & 1;
    bf16x8 nb0;
    if (ks < 30) nb0 = *(const bf16x8*)(gB + 32 * (ks + 2));
    bf16x8 A0 = *(const bf16x8*)(a0 + 32 * ks);
#pragma unroll
    for (int nt = 0; nt < 2; ++nt) {
      bf16x8 B = *(const bf16x8*)&Bs[bufc][32 * wcol + 16 * nt + ln][q8];
      acc[nt] = __builtin_amdgcn_mfma_f32_16x16x32_bf16(A0, B, acc[nt], 0, 0, 0);
    }
    if (ks < 31) *(bf16x8*)&Bs[bufc ^ 1][brow][bseg] = cb0;
    __syncthreads();
    if (ks < 30) cb0 = nb0;
  }
#pragma unroll
  for (int nt = 0; nt < 2; ++nt) {
    int cg = n0 + 32 * wcol + 16 * nt + ln;
#pragma unroll
    for (int reg = 0; reg < 4; ++reg) {
      int rr = i0 + 16 * wr + quad * 4 + reg;
      YACC[(size_t)rr * DIN + cg] = acc[nt][reg];
    }
  }
}

// ---------------- bias + residual + LayerNorm (shuffle-reduce, 2 barriers) --------
__global__ __launch_bounds__(256) void k_ln(const float* __restrict__ YACC,
                                            const float* __restrict__ x,
                                            const float* __restrict__ wo_b,
                                            const float* __restrict__ g,
                                            const float* __restrict__ b,
                                            float* __restrict__ y) {
  const int i = blockIdx.x;
  const int tid = threadIdx.x;
  const int lane = tid & 63, wave = tid >> 6;
  float v[3];
#pragma unroll
  for (int t = 0; t < 3; ++t) {
    int cc = tid + t * 256;
    v[t] = YACC[(size_t)i * DIN + cc] + wo_b[cc] + x[(size_t)i * DIN + cc];
  }
  __shared__ float p1[4], p2[4];
  float s = v[0] + v[1] + v[2];
#pragma unroll
  for (int off = 1; off < 64; off <<= 1) s += __shfl_xor(s, off);
  if (lane == 0) p1[wave] = s;
  __syncthreads();
  const float mu = (p1[0] + p1[1] + p1[2] + p1[3]) * (1.0f / DIN);
  float q = 0.f;
#pragma unroll
  for (int t = 0; t < 3; ++t) {
    float d = v[t] - mu;
    q += d * d;
  }
#pragma unroll
  for (int off = 1; off < 64; off <<= 1) q += __shfl_xor(q, off);
  if (lane == 0) p2[wave] = q;
  __syncthreads();
  const float rs = rsqrtf((p2[0] + p2[1] + p2[2] + p2[3]) * (1.0f / DIN) + EPSF);
#pragma unroll
  for (int t = 0; t < 3; ++t) {
    int cc = tid + t * 256;
    y[(size_t)i * DIN + cc] = (v[t] - mu) * rs * g[cc] + b[cc];
  }
}

extern "C" void kernel_launch(void* const* d_in, const int* in_sizes, int n_in,
                              void* d_out, int out_size, void* d_ws, size_t ws_size,
                              hipStream_t stream) {
  (void)in_sizes; (void)n_in; (void)out_size; (void)ws_size;
  const float* x       = (const float*)d_in[0];
  const int*   batch   = (const int*)d_in[1];
  const float* motif   = (const float*)d_in[2];
  const float* wq_w    = (const float*)d_in[3];
  const float* wq_b    = (const float*)d_in[4];
  const float* wk_w    = (const float*)d_in[5];
  const float* wk_b    = (const float*)d_in[6];
  const float* wv_w    = (const float*)d_in[7];
  const float* wv_b    = (const float*)d_in[8];
  const float* wo_w    = (const float*)d_in[9];
  const float* wo_b    = (const float*)d_in[10];
  const float* ln_g    = (const float*)d_in[11];
  const float* ln_b    = (const float*)d_in[12];
  const float* alpha_p = (const float*)d_in[13];
  const float* beta_p  = (const float*)d_in[14];
  const float* gq_w    = (const float*)d_in[15];
  const float* gq_b    = (const float*)d_in[16];
  const float* gk_w    = (const float*)d_in[17];
  const float* gk_b    = (const float*)d_in[18];
  const float* headW   = (const float*)d_in[19];

  float* y    = (float*)d_out;
  float* ATTN = (float*)d_out + (size_t)NN * DIN;
  float* ws   = (float*)d_ws;
  short* Obf  = (short*)(ws + OFF_OBF);
  short* wot  = (short*)(ws + OFF_WOT);
  float* YACC = ws + OFF_YACC;
  short* Qb   = (short*)(ws + OFF_Q);
  short* Kb   = (short*)(ws + OFF_K);
  short* Vb   = (short*)(ws + OFF_VB);
  short* Vt   = (short*)(ws + OFF_VT);
  short* xb   = (short*)(ws + OFF_XB);
  short* Wt   = (short*)(ws + OFF_WT);
  float* GQ   = ws + OFF_GQ;
  float* GK   = ws + OFF_GK;

  k_prep<<<2304, 256, 0, stream>>>(x, xb, wq_w, wk_w, wv_w, Wt, wo_w, wot);
  k_qkv<<<dim3(24, 32), 256, 0, stream>>>(xb, Wt, wq_b, wk_b, wv_b, Qb, Kb, Vb);
  k_vtg<<<384, 256, 0, stream>>>(Qb, Kb, gq_w, gq_b, gk_w, gk_b, GQ, GK, Vb, Vt);
  k_sa<<<dim3(64, 64), 256, 0, stream>>>(Qb, Kb, batch, motif, GQ, GK, headW,
                                         alpha_p, beta_p, ATTN);
  k_pv<<<1024, 256, 0, stream>>>(ATTN, Vt, Obf);
  k_outproj<<<dim3(12, 64), 256, 0, stream>>>(Obf, wot, YACC);
  k_ln<<<NN, 256, 0, stream>>>(YACC, x, wo_b, ln_g, ln_b, y);
}